// Round 3
// baseline (1105.926 us; speedup 1.0000x reference)
//
#include <hip/hip_runtime.h>

#define N_NODES 100000
#define E_EDGES 1600000
#define DIM 128
#define HID 64
#define NGRAPH 8
#define EPSBN 1e-5f

#define NBKT ((N_NODES + 63) / 64)   // 1563 buckets of 64 nodes
#define BKT_CAP 1536                 // mean 1024, sigma 32 -> 16-sigma margin
#define SCAN_BLK 1024
#define NSCAN_BLKS ((N_NODES + SCAN_BLK - 1) / SCAN_BLK)  // 98

// ---------------------------------------------------------------------------
// bscatter: edges -> dst-range buckets. Writes stream per-bucket (write amp~1).
// ---------------------------------------------------------------------------
__global__ __launch_bounds__(256) void bscatter_kernel(
    const int* __restrict__ src, const int* __restrict__ dst,
    int* __restrict__ bktcnt, unsigned* __restrict__ bktbuf) {
  int e = blockIdx.x * blockDim.x + threadIdx.x;
  if (e >= E_EDGES) return;
  int d = dst[e];
  int b = d >> 6;
  int pos = atomicAdd(&bktcnt[b], 1);
  if (pos < BKT_CAP)
    bktbuf[(size_t)b * BKT_CAP + pos] =
        ((unsigned)(d & 63) << 17) | (unsigned)src[e];
}

// ---------------------------------------------------------------------------
// bhist: per-bucket LDS histogram -> deg[64 nodes], coalesced write
// ---------------------------------------------------------------------------
__global__ __launch_bounds__(256) void bhist_kernel(
    const int* __restrict__ bktcnt, const unsigned* __restrict__ bktbuf,
    int* __restrict__ deg) {
  __shared__ int h[64];
  int b = blockIdx.x;
  int t = threadIdx.x;
  if (t < 64) h[t] = 0;
  __syncthreads();
  int cnt = bktcnt[b];
  cnt = cnt < BKT_CAP ? cnt : BKT_CAP;
  const unsigned* buf = bktbuf + (size_t)b * BKT_CAP;
  for (int i = t; i < cnt; i += 256) atomicAdd(&h[buf[i] >> 17], 1);
  __syncthreads();
  int n0 = b << 6;
  if (t < 64 && n0 + t < N_NODES) deg[n0 + t] = h[t];
}

// ---------------------------------------------------------------------------
// scanA: per-block inclusive scan of deg -> rowptr+1 partial, block sums
// ---------------------------------------------------------------------------
__global__ __launch_bounds__(SCAN_BLK) void scanA_kernel(
    const int* __restrict__ deg, int* __restrict__ incl,
    int* __restrict__ bsum) {
  __shared__ int buf[SCAN_BLK];
  int gid = blockIdx.x * SCAN_BLK + threadIdx.x;
  int v = (gid < N_NODES) ? deg[gid] : 0;
  buf[threadIdx.x] = v;
  __syncthreads();
  for (int off = 1; off < SCAN_BLK; off <<= 1) {
    int t = buf[threadIdx.x];
    int add = (threadIdx.x >= off) ? buf[threadIdx.x - off] : 0;
    __syncthreads();
    buf[threadIdx.x] = t + add;
    __syncthreads();
  }
  if (gid < N_NODES) incl[gid] = buf[threadIdx.x];
  if (threadIdx.x == SCAN_BLK - 1) bsum[blockIdx.x] = buf[SCAN_BLK - 1];
}

__global__ __launch_bounds__(128) void scanB_kernel(int* __restrict__ bsum) {
  __shared__ int buf[128];
  int tid = threadIdx.x;
  buf[tid] = (tid < NSCAN_BLKS) ? bsum[tid] : 0;
  __syncthreads();
  for (int off = 1; off < 128; off <<= 1) {
    int t = buf[tid];
    int add = (tid >= off) ? buf[tid - off] : 0;
    __syncthreads();
    buf[tid] = t + add;
    __syncthreads();
  }
  if (tid < NSCAN_BLKS) bsum[tid] = buf[tid];
}

__global__ __launch_bounds__(256) void scanC_kernel(
    int* __restrict__ rowptr, const int* __restrict__ bsum) {
  int i = blockIdx.x * blockDim.x + threadIdx.x;
  if (i >= N_NODES) return;
  int blk = i >> 10;
  int off = (blk > 0) ? bsum[blk - 1] : 0;
  rowptr[i + 1] += off;
  if (i == 0) rowptr[0] = 0;
}

// ---------------------------------------------------------------------------
// emit: per-bucket counting sort into csr; each bucket's csr window is
// contiguous (~4KB) -> full-line writes in L2
// ---------------------------------------------------------------------------
__global__ __launch_bounds__(256) void emit_kernel(
    const int* __restrict__ bktcnt, const unsigned* __restrict__ bktbuf,
    const int* __restrict__ rowptr, int* __restrict__ csr) {
  __shared__ int lcnt[64];
  __shared__ int base[64];
  int b = blockIdx.x;
  int t = threadIdx.x;
  int n0 = b << 6;
  if (t < 64) {
    lcnt[t] = 0;
    base[t] = (n0 + t < N_NODES) ? rowptr[n0 + t] : 0;
  }
  __syncthreads();
  int cnt = bktcnt[b];
  cnt = cnt < BKT_CAP ? cnt : BKT_CAP;
  const unsigned* buf = bktbuf + (size_t)b * BKT_CAP;
  for (int i = t; i < cnt; i += 256) {
    unsigned p = buf[i];
    int dloc = p >> 17;
    int slot = base[dloc] + atomicAdd(&lcnt[dloc], 1);
    csr[slot] = (int)(p & 0x1FFFFu);
  }
}

// ---------------------------------------------------------------------------
// mm1: y1 = x@W1l, y2 = x@W1r. 4 threads/row, 16 cols each, both mats.
// 400k threads -> ~6 waves/SIMD.
// ---------------------------------------------------------------------------
__global__ __launch_bounds__(256) void mm1_kernel(
    const float* __restrict__ x, const float* __restrict__ W1l,
    const float* __restrict__ W1r, float* __restrict__ y1,
    float* __restrict__ y2) {
  int t = blockIdx.x * blockDim.x + threadIdx.x;
  int n = t >> 2;
  if (n >= N_NODES) return;
  int c0 = (t & 3) << 4;
  const float* xr = x + (size_t)n * DIM;
  const float* w1 = W1l + c0;
  const float* w2 = W1r + c0;

  float a1[16], a2[16];
  #pragma unroll
  for (int j = 0; j < 16; ++j) { a1[j] = 0.f; a2[j] = 0.f; }

  for (int k = 0; k < DIM; k += 4) {
    float4 xv = *reinterpret_cast<const float4*>(xr + k);
    float xs[4] = {xv.x, xv.y, xv.z, xv.w};
    #pragma unroll
    for (int kk = 0; kk < 4; ++kk) {
      float xk = xs[kk];
      const float4* w1p = reinterpret_cast<const float4*>(w1 + (k + kk) * HID);
      const float4* w2p = reinterpret_cast<const float4*>(w2 + (k + kk) * HID);
      #pragma unroll
      for (int q = 0; q < 4; ++q) {
        float4 v1 = w1p[q];
        float4 v2 = w2p[q];
        a1[4*q+0] = fmaf(xk, v1.x, a1[4*q+0]);
        a1[4*q+1] = fmaf(xk, v1.y, a1[4*q+1]);
        a1[4*q+2] = fmaf(xk, v1.z, a1[4*q+2]);
        a1[4*q+3] = fmaf(xk, v1.w, a1[4*q+3]);
        a2[4*q+0] = fmaf(xk, v2.x, a2[4*q+0]);
        a2[4*q+1] = fmaf(xk, v2.y, a2[4*q+1]);
        a2[4*q+2] = fmaf(xk, v2.z, a2[4*q+2]);
        a2[4*q+3] = fmaf(xk, v2.w, a2[4*q+3]);
      }
    }
  }
  float4* o1 = reinterpret_cast<float4*>(y1 + (size_t)n * HID + c0);
  float4* o2 = reinterpret_cast<float4*>(y2 + (size_t)n * HID + c0);
  #pragma unroll
  for (int q = 0; q < 4; ++q) {
    o1[q] = make_float4(a1[4*q], a1[4*q+1], a1[4*q+2], a1[4*q+3]);
    o2[q] = make_float4(a2[4*q], a2[4*q+1], a2[4*q+2], a2[4*q+3]);
  }
}

// ---------------------------------------------------------------------------
// mm2: h = relu(hraw*scale+shift) streamed; z1 = h@W2l, z2 = h@W2r.
// Same 4-threads/row split.
// ---------------------------------------------------------------------------
__global__ __launch_bounds__(256) void mm2_kernel(
    const float* __restrict__ C, const float* __restrict__ scsh,
    const float* __restrict__ W2l, const float* __restrict__ W2r,
    float* __restrict__ z1, float* __restrict__ z2) {
  int t = blockIdx.x * blockDim.x + threadIdx.x;
  int n = t >> 2;
  if (n >= N_NODES) return;
  int c0 = (t & 3) << 4;
  const float* hr = C + (size_t)n * HID;
  const float* w1 = W2l + c0;
  const float* w2 = W2r + c0;

  float a1[16], a2[16];
  #pragma unroll
  for (int j = 0; j < 16; ++j) { a1[j] = 0.f; a2[j] = 0.f; }

  for (int k = 0; k < HID; k += 4) {
    float4 hv = *reinterpret_cast<const float4*>(hr + k);
    float hs[4] = {hv.x, hv.y, hv.z, hv.w};
    #pragma unroll
    for (int kk = 0; kk < 4; ++kk) {
      float hk = fmaf(hs[kk], scsh[k + kk], scsh[HID + k + kk]);
      hk = hk > 0.f ? hk : 0.f;
      const float4* w1p = reinterpret_cast<const float4*>(w1 + (k + kk) * HID);
      const float4* w2p = reinterpret_cast<const float4*>(w2 + (k + kk) * HID);
      #pragma unroll
      for (int q = 0; q < 4; ++q) {
        float4 v1 = w1p[q];
        float4 v2 = w2p[q];
        a1[4*q+0] = fmaf(hk, v1.x, a1[4*q+0]);
        a1[4*q+1] = fmaf(hk, v1.y, a1[4*q+1]);
        a1[4*q+2] = fmaf(hk, v1.z, a1[4*q+2]);
        a1[4*q+3] = fmaf(hk, v1.w, a1[4*q+3]);
        a2[4*q+0] = fmaf(hk, v2.x, a2[4*q+0]);
        a2[4*q+1] = fmaf(hk, v2.y, a2[4*q+1]);
        a2[4*q+2] = fmaf(hk, v2.z, a2[4*q+2]);
        a2[4*q+3] = fmaf(hk, v2.w, a2[4*q+3]);
      }
    }
  }
  float4* o1 = reinterpret_cast<float4*>(z1 + (size_t)n * HID + c0);
  float4* o2 = reinterpret_cast<float4*>(z2 + (size_t)n * HID + c0);
  #pragma unroll
  for (int q = 0; q < 4; ++q) {
    o1[q] = make_float4(a1[4*q], a1[4*q+1], a1[4*q+2], a1[4*q+3]);
    o2[q] = make_float4(a2[4*q], a2[4*q+1], a2[4*q+2], a2[4*q+3]);
  }
}

// ---------------------------------------------------------------------------
// gather: one wave per node (grid-stride); out = mean(y[src]) + bias + other.
// STATS: accumulate per-column sum/sumsq in registers, flush once per block.
// ---------------------------------------------------------------------------
template <bool STATS>
__global__ __launch_bounds__(256) void gather_kernel(
    const float* __restrict__ y, const int* __restrict__ csr,
    const int* __restrict__ rowptr, const float* __restrict__ other,
    const float* __restrict__ bias, float* __restrict__ outC,
    float* __restrict__ stats) {
  int lane = threadIdx.x & 63;
  int wid = (blockIdx.x * blockDim.x + threadIdx.x) >> 6;
  int nw = (gridDim.x * blockDim.x) >> 6;
  float bj = bias[lane];
  float lsum = 0.f, lsq = 0.f;

  for (int n = wid; n < N_NODES; n += nw) {
    int start = rowptr[n];
    int end = rowptr[n + 1];
    float acc = 0.f;
    for (int bse = start; bse < end; bse += 64) {
      int e = bse + lane;
      int s = (e < end) ? csr[e] : 0;
      int m = end - bse;
      m = m < 64 ? m : 64;
      float a0 = 0.f, a1 = 0.f, a2 = 0.f, a3 = 0.f;
      int i = 0;
      for (; i + 4 <= m; i += 4) {
        int s0 = __shfl(s, i);
        int s1 = __shfl(s, i + 1);
        int s2 = __shfl(s, i + 2);
        int s3 = __shfl(s, i + 3);
        a0 += y[(size_t)s0 * HID + lane];
        a1 += y[(size_t)s1 * HID + lane];
        a2 += y[(size_t)s2 * HID + lane];
        a3 += y[(size_t)s3 * HID + lane];
      }
      for (; i < m; ++i) a0 += y[(size_t)__shfl(s, i) * HID + lane];
      acc += (a0 + a1) + (a2 + a3);
    }
    int deg = end - start;
    float inv = 1.f / (float)(deg > 1 ? deg : 1);
    float val = acc * inv + bj + other[(size_t)n * HID + lane];
    outC[(size_t)n * HID + lane] = val;
    if (STATS) {
      lsum += val;
      lsq = fmaf(val, val, lsq);
    }
  }

  if (STATS) {
    __shared__ float ss[HID];
    __shared__ float sq[HID];
    int t = threadIdx.x;
    if (t < HID) { ss[t] = 0.f; sq[t] = 0.f; }
    __syncthreads();
    atomicAdd(&ss[lane], lsum);
    atomicAdd(&sq[lane], lsq);
    __syncthreads();
    if (t < HID) {
      unsafeAtomicAdd(&stats[t], ss[t]);
      unsafeAtomicAdd(&stats[HID + t], sq[t]);
    }
  }
}

// ---------------------------------------------------------------------------
__global__ void bnstats_kernel(const float* __restrict__ stats,
                               const float* __restrict__ gamma,
                               const float* __restrict__ beta,
                               float* __restrict__ scsh) {
  int j = threadIdx.x;  // 64 threads
  float inv_n = 1.0f / (float)N_NODES;
  float mu = stats[j] * inv_n;
  float var = stats[HID + j] * inv_n - mu * mu;
  float sc = gamma[j] * rsqrtf(var + EPSBN);
  scsh[j] = sc;
  scsh[HID + j] = beta[j] - mu * sc;
}

// ---------------------------------------------------------------------------
// pool: per-graph mean of h2 (batch sorted -> register accumulate, flush on
// boundary)
// ---------------------------------------------------------------------------
#define POOL_WAVES 2048
__global__ __launch_bounds__(256) void pool_kernel(
    const float* __restrict__ h2, const int* __restrict__ batch,
    float* __restrict__ poolacc, float* __restrict__ poolcnt) {
  int wave = (blockIdx.x * blockDim.x + threadIdx.x) >> 6;
  int j = threadIdx.x & 63;
  const int chunk = (N_NODES + POOL_WAVES - 1) / POOL_WAVES;
  int n0 = wave * chunk;
  int n1 = n0 + chunk;
  n1 = n1 < N_NODES ? n1 : N_NODES;
  if (n0 >= n1) return;
  bool docnt = (j == 0);

  int curb = -1;
  float accv = 0.f, cntv = 0.f;
  for (int n = n0; n < n1; ++n) {
    float val = h2[(size_t)n * HID + j];
    int b = batch[n];
    if (b != curb) {
      if (curb >= 0) {
        unsafeAtomicAdd(&poolacc[curb * HID + j], accv);
        if (docnt) unsafeAtomicAdd(&poolcnt[curb], cntv);
      }
      curb = b;
      accv = 0.f;
      cntv = 0.f;
    }
    accv += val;
    cntv += 1.f;
  }
  if (curb >= 0) {
    unsafeAtomicAdd(&poolacc[curb * HID + j], accv);
    if (docnt) unsafeAtomicAdd(&poolcnt[curb], cntv);
  }
}

// ---------------------------------------------------------------------------
__global__ void final_kernel(const float* __restrict__ poolacc,
                             const float* __restrict__ poolcnt,
                             float* __restrict__ out) {
  int t = blockIdx.x * blockDim.x + threadIdx.x;
  if (t >= NGRAPH * HID) return;
  int b = t >> 6;
  float c = poolcnt[b];
  c = c > 1.f ? c : 1.f;
  out[t] = poolacc[t] / c;
}

// ---------------------------------------------------------------------------
extern "C" void kernel_launch(void* const* d_in, const int* in_sizes, int n_in,
                              void* d_out, int out_size, void* d_ws,
                              size_t ws_size, hipStream_t stream) {
  const float* x      = (const float*)d_in[0];
  const int*   ei     = (const int*)d_in[1];
  const int*   batch  = (const int*)d_in[2];
  const float* W1l    = (const float*)d_in[3];
  const float* b1     = (const float*)d_in[4];
  const float* W1r    = (const float*)d_in[5];
  const float* gamma1 = (const float*)d_in[6];
  const float* beta1  = (const float*)d_in[7];
  const float* W2l    = (const float*)d_in[8];
  const float* b2     = (const float*)d_in[9];
  const float* W2r    = (const float*)d_in[10];

  const int* src = ei;            // edge_index[0]
  const int* dst = ei + E_EDGES;  // edge_index[1]

  float* ws = (float*)d_ws;
  size_t off = 0;
  float* A  = ws + off; off += (size_t)N_NODES * HID;  // y1 -> z1
  float* Bb = ws + off; off += (size_t)N_NODES * HID;  // y2 -> z2
  float* Cc = ws + off; off += (size_t)N_NODES * HID;  // h_raw / h2
  // zero-region start
  int* bktcnt   = (int*)(ws + off); off += NBKT;
  float* stats  = ws + off; off += 2 * HID;
  float* poolacc= ws + off; off += NGRAPH * HID;
  float* poolcnt= ws + off; off += NGRAPH;
  size_t zero_elems = NBKT + 2 * HID + NGRAPH * HID + NGRAPH;
  // zero-region end
  float* scsh   = ws + off; off += 2 * HID;
  int* deg      = (int*)(ws + off); off += N_NODES;
  int* rowptr   = (int*)(ws + off); off += N_NODES + 1;
  int* bsum     = (int*)(ws + off); off += 128;
  int* csr      = (int*)(ws + off); off += E_EDGES;
  unsigned* bktbuf = (unsigned*)(ws + off); off += (size_t)NBKT * BKT_CAP;

  hipMemsetAsync(bktcnt, 0, zero_elems * sizeof(float), stream);

  // ---- CSR build ----
  bscatter_kernel<<<(E_EDGES + 255) / 256, 256, 0, stream>>>(src, dst, bktcnt,
                                                             bktbuf);
  bhist_kernel<<<NBKT, 256, 0, stream>>>(bktcnt, bktbuf, deg);
  scanA_kernel<<<NSCAN_BLKS, SCAN_BLK, 0, stream>>>(deg, rowptr + 1, bsum);
  scanB_kernel<<<1, 128, 0, stream>>>(bsum);
  scanC_kernel<<<(N_NODES + 255) / 256, 256, 0, stream>>>(rowptr, bsum);
  emit_kernel<<<NBKT, 256, 0, stream>>>(bktcnt, bktbuf, rowptr, csr);

  // ---- layer 1 ----
  mm1_kernel<<<(N_NODES * 4 + 255) / 256, 256, 0, stream>>>(x, W1l, W1r, A,
                                                            Bb);
  gather_kernel<true><<<2048, 256, 0, stream>>>(A, csr, rowptr, Bb, b1, Cc,
                                                stats);
  bnstats_kernel<<<1, 64, 0, stream>>>(stats, gamma1, beta1, scsh);

  // ---- layer 2 ----
  mm2_kernel<<<(N_NODES * 4 + 255) / 256, 256, 0, stream>>>(Cc, scsh, W2l,
                                                            W2r, A, Bb);
  gather_kernel<false><<<2048, 256, 0, stream>>>(A, csr, rowptr, Bb, b2, Cc,
                                                 nullptr);
  pool_kernel<<<(POOL_WAVES * 64 + 255) / 256, 256, 0, stream>>>(
      Cc, batch, poolacc, poolcnt);
  final_kernel<<<2, 256, 0, stream>>>(poolacc, poolcnt, (float*)d_out);
}

// Round 4
// 585.799 us; speedup vs baseline: 1.8879x; 1.8879x over previous
//
#include <hip/hip_runtime.h>

#define N_NODES 100000
#define E_EDGES 1600000
#define DIM 128
#define HID 64
#define NGRAPH 8
#define EPSBN 1e-5f

#define NBKT ((N_NODES + 63) / 64)   // 1563 buckets of 64 nodes
#define BKT_CAP 1536                 // mean 1024, sigma 32 -> 16-sigma margin
#define SCAN_BLK 1024
#define NSCAN_BLKS ((N_NODES + SCAN_BLK - 1) / SCAN_BLK)  // 98

// ---------------------------------------------------------------------------
// bscatter: edges -> dst-range buckets. Writes stream per-bucket (write amp~1).
// ---------------------------------------------------------------------------
__global__ __launch_bounds__(256) void bscatter_kernel(
    const int* __restrict__ src, const int* __restrict__ dst,
    int* __restrict__ bktcnt, unsigned* __restrict__ bktbuf) {
  int e = blockIdx.x * blockDim.x + threadIdx.x;
  if (e >= E_EDGES) return;
  int d = dst[e];
  int b = d >> 6;
  int pos = atomicAdd(&bktcnt[b], 1);
  if (pos < BKT_CAP)
    bktbuf[(size_t)b * BKT_CAP + pos] =
        ((unsigned)(d & 63) << 17) | (unsigned)src[e];
}

// ---------------------------------------------------------------------------
// bhist: per-bucket LDS histogram -> deg[64 nodes], coalesced write
// ---------------------------------------------------------------------------
__global__ __launch_bounds__(256) void bhist_kernel(
    const int* __restrict__ bktcnt, const unsigned* __restrict__ bktbuf,
    int* __restrict__ deg) {
  __shared__ int h[64];
  int b = blockIdx.x;
  int t = threadIdx.x;
  if (t < 64) h[t] = 0;
  __syncthreads();
  int cnt = bktcnt[b];
  cnt = cnt < BKT_CAP ? cnt : BKT_CAP;
  const unsigned* buf = bktbuf + (size_t)b * BKT_CAP;
  for (int i = t; i < cnt; i += 256) atomicAdd(&h[buf[i] >> 17], 1);
  __syncthreads();
  int n0 = b << 6;
  if (t < 64 && n0 + t < N_NODES) deg[n0 + t] = h[t];
}

// ---------------------------------------------------------------------------
// scanA: per-block inclusive scan of deg -> rowptr+1 partial, block sums
// ---------------------------------------------------------------------------
__global__ __launch_bounds__(SCAN_BLK) void scanA_kernel(
    const int* __restrict__ deg, int* __restrict__ incl,
    int* __restrict__ bsum) {
  __shared__ int buf[SCAN_BLK];
  int gid = blockIdx.x * SCAN_BLK + threadIdx.x;
  int v = (gid < N_NODES) ? deg[gid] : 0;
  buf[threadIdx.x] = v;
  __syncthreads();
  for (int off = 1; off < SCAN_BLK; off <<= 1) {
    int t = buf[threadIdx.x];
    int add = (threadIdx.x >= off) ? buf[threadIdx.x - off] : 0;
    __syncthreads();
    buf[threadIdx.x] = t + add;
    __syncthreads();
  }
  if (gid < N_NODES) incl[gid] = buf[threadIdx.x];
  if (threadIdx.x == SCAN_BLK - 1) bsum[blockIdx.x] = buf[SCAN_BLK - 1];
}

__global__ __launch_bounds__(128) void scanB_kernel(int* __restrict__ bsum) {
  __shared__ int buf[128];
  int tid = threadIdx.x;
  buf[tid] = (tid < NSCAN_BLKS) ? bsum[tid] : 0;
  __syncthreads();
  for (int off = 1; off < 128; off <<= 1) {
    int t = buf[tid];
    int add = (tid >= off) ? buf[tid - off] : 0;
    __syncthreads();
    buf[tid] = t + add;
    __syncthreads();
  }
  if (tid < NSCAN_BLKS) bsum[tid] = buf[tid];
}

__global__ __launch_bounds__(256) void scanC_kernel(
    int* __restrict__ rowptr, const int* __restrict__ bsum) {
  int i = blockIdx.x * blockDim.x + threadIdx.x;
  if (i >= N_NODES) return;
  int blk = i >> 10;
  int off = (blk > 0) ? bsum[blk - 1] : 0;
  rowptr[i + 1] += off;
  if (i == 0) rowptr[0] = 0;
}

// ---------------------------------------------------------------------------
// emit: per-bucket counting sort into csr; each bucket's csr window is
// contiguous (~4KB) -> full-line writes in L2
// ---------------------------------------------------------------------------
__global__ __launch_bounds__(256) void emit_kernel(
    const int* __restrict__ bktcnt, const unsigned* __restrict__ bktbuf,
    const int* __restrict__ rowptr, int* __restrict__ csr) {
  __shared__ int lcnt[64];
  __shared__ int base[64];
  int b = blockIdx.x;
  int t = threadIdx.x;
  int n0 = b << 6;
  if (t < 64) {
    lcnt[t] = 0;
    base[t] = (n0 + t < N_NODES) ? rowptr[n0 + t] : 0;
  }
  __syncthreads();
  int cnt = bktcnt[b];
  cnt = cnt < BKT_CAP ? cnt : BKT_CAP;
  const unsigned* buf = bktbuf + (size_t)b * BKT_CAP;
  for (int i = t; i < cnt; i += 256) {
    unsigned p = buf[i];
    int dloc = p >> 17;
    int slot = base[dloc] + atomicAdd(&lcnt[dloc], 1);
    csr[slot] = (int)(p & 0x1FFFFu);
  }
}

// ---------------------------------------------------------------------------
// mm1: y1 = x@W1l, y2 = x@W1r.  Block = 64 rows x 4 waves; wave w owns cols
// [w*16, w*16+16) of BOTH outputs.  c0 is wave-uniform (readfirstlane) so W
// loads stay scalarized (s_load, SGPR broadcast).  1563 blocks ~ 6 waves/SIMD.
// ---------------------------------------------------------------------------
__global__ __launch_bounds__(256) void mm1_kernel(
    const float* __restrict__ x, const float* __restrict__ W1l,
    const float* __restrict__ W1r, float* __restrict__ y1,
    float* __restrict__ y2) {
  int lane = threadIdx.x & 63;
  int c0 = __builtin_amdgcn_readfirstlane((int)(threadIdx.x >> 6) << 4);
  int n = blockIdx.x * 64 + lane;
  if (n >= N_NODES) return;
  const float* xr = x + (size_t)n * DIM;

  float a1[16], a2[16];
  #pragma unroll
  for (int j = 0; j < 16; ++j) { a1[j] = 0.f; a2[j] = 0.f; }

  for (int k = 0; k < DIM; k += 4) {
    float4 xv = *reinterpret_cast<const float4*>(xr + k);
    float xs[4] = {xv.x, xv.y, xv.z, xv.w};
    #pragma unroll
    for (int kk = 0; kk < 4; ++kk) {
      const float* w1 = W1l + (size_t)(k + kk) * HID + c0;  // uniform addr
      const float* w2 = W1r + (size_t)(k + kk) * HID + c0;  // uniform addr
      float xk = xs[kk];
      #pragma unroll
      for (int j = 0; j < 16; ++j) {
        a1[j] = fmaf(xk, w1[j], a1[j]);
        a2[j] = fmaf(xk, w2[j], a2[j]);
      }
    }
  }
  float* o1 = y1 + (size_t)n * HID + c0;
  float* o2 = y2 + (size_t)n * HID + c0;
  #pragma unroll
  for (int q = 0; q < 4; ++q) {
    *reinterpret_cast<float4*>(o1 + 4 * q) =
        make_float4(a1[4*q], a1[4*q+1], a1[4*q+2], a1[4*q+3]);
    *reinterpret_cast<float4*>(o2 + 4 * q) =
        make_float4(a2[4*q], a2[4*q+1], a2[4*q+2], a2[4*q+3]);
  }
}

// ---------------------------------------------------------------------------
// mm2: h = relu(hraw*scale+shift) (scsh uniform -> s_load); z1=h@W2l, z2=h@W2r.
// Same wave-level column split as mm1.
// ---------------------------------------------------------------------------
__global__ __launch_bounds__(256) void mm2_kernel(
    const float* __restrict__ C, const float* __restrict__ scsh,
    const float* __restrict__ W2l, const float* __restrict__ W2r,
    float* __restrict__ z1, float* __restrict__ z2) {
  int lane = threadIdx.x & 63;
  int c0 = __builtin_amdgcn_readfirstlane((int)(threadIdx.x >> 6) << 4);
  int n = blockIdx.x * 64 + lane;
  if (n >= N_NODES) return;
  const float* hr = C + (size_t)n * HID;

  float a1[16], a2[16];
  #pragma unroll
  for (int j = 0; j < 16; ++j) { a1[j] = 0.f; a2[j] = 0.f; }

  for (int k = 0; k < HID; k += 4) {
    float4 hv = *reinterpret_cast<const float4*>(hr + k);
    float hs[4] = {hv.x, hv.y, hv.z, hv.w};
    #pragma unroll
    for (int kk = 0; kk < 4; ++kk) {
      float hk = fmaf(hs[kk], scsh[k + kk], scsh[HID + k + kk]);
      hk = hk > 0.f ? hk : 0.f;
      const float* w1 = W2l + (size_t)(k + kk) * HID + c0;  // uniform addr
      const float* w2 = W2r + (size_t)(k + kk) * HID + c0;  // uniform addr
      #pragma unroll
      for (int j = 0; j < 16; ++j) {
        a1[j] = fmaf(hk, w1[j], a1[j]);
        a2[j] = fmaf(hk, w2[j], a2[j]);
      }
    }
  }
  float* o1 = z1 + (size_t)n * HID + c0;
  float* o2 = z2 + (size_t)n * HID + c0;
  #pragma unroll
  for (int q = 0; q < 4; ++q) {
    *reinterpret_cast<float4*>(o1 + 4 * q) =
        make_float4(a1[4*q], a1[4*q+1], a1[4*q+2], a1[4*q+3]);
    *reinterpret_cast<float4*>(o2 + 4 * q) =
        make_float4(a2[4*q], a2[4*q+1], a2[4*q+2], a2[4*q+3]);
  }
}

// ---------------------------------------------------------------------------
// gather: one wave per node (grid-stride); out = mean(y[src]) + bias + other.
// STATS: accumulate per-column sum/sumsq in registers, flush once per block.
// ---------------------------------------------------------------------------
template <bool STATS>
__global__ __launch_bounds__(256) void gather_kernel(
    const float* __restrict__ y, const int* __restrict__ csr,
    const int* __restrict__ rowptr, const float* __restrict__ other,
    const float* __restrict__ bias, float* __restrict__ outC,
    float* __restrict__ stats) {
  int lane = threadIdx.x & 63;
  int wid = (blockIdx.x * blockDim.x + threadIdx.x) >> 6;
  int nw = (gridDim.x * blockDim.x) >> 6;
  float bj = bias[lane];
  float lsum = 0.f, lsq = 0.f;

  for (int n = wid; n < N_NODES; n += nw) {
    int start = rowptr[n];
    int end = rowptr[n + 1];
    float acc = 0.f;
    for (int bse = start; bse < end; bse += 64) {
      int e = bse + lane;
      int s = (e < end) ? csr[e] : 0;
      int m = end - bse;
      m = m < 64 ? m : 64;
      float a0 = 0.f, a1 = 0.f, a2 = 0.f, a3 = 0.f;
      int i = 0;
      for (; i + 4 <= m; i += 4) {
        int s0 = __shfl(s, i);
        int s1 = __shfl(s, i + 1);
        int s2 = __shfl(s, i + 2);
        int s3 = __shfl(s, i + 3);
        a0 += y[(size_t)s0 * HID + lane];
        a1 += y[(size_t)s1 * HID + lane];
        a2 += y[(size_t)s2 * HID + lane];
        a3 += y[(size_t)s3 * HID + lane];
      }
      for (; i < m; ++i) a0 += y[(size_t)__shfl(s, i) * HID + lane];
      acc += (a0 + a1) + (a2 + a3);
    }
    int deg = end - start;
    float inv = 1.f / (float)(deg > 1 ? deg : 1);
    float val = acc * inv + bj + other[(size_t)n * HID + lane];
    outC[(size_t)n * HID + lane] = val;
    if (STATS) {
      lsum += val;
      lsq = fmaf(val, val, lsq);
    }
  }

  if (STATS) {
    __shared__ float ss[HID];
    __shared__ float sq[HID];
    int t = threadIdx.x;
    if (t < HID) { ss[t] = 0.f; sq[t] = 0.f; }
    __syncthreads();
    atomicAdd(&ss[lane], lsum);
    atomicAdd(&sq[lane], lsq);
    __syncthreads();
    if (t < HID) {
      unsafeAtomicAdd(&stats[t], ss[t]);
      unsafeAtomicAdd(&stats[HID + t], sq[t]);
    }
  }
}

// ---------------------------------------------------------------------------
__global__ void bnstats_kernel(const float* __restrict__ stats,
                               const float* __restrict__ gamma,
                               const float* __restrict__ beta,
                               float* __restrict__ scsh) {
  int j = threadIdx.x;  // 64 threads
  float inv_n = 1.0f / (float)N_NODES;
  float mu = stats[j] * inv_n;
  float var = stats[HID + j] * inv_n - mu * mu;
  float sc = gamma[j] * rsqrtf(var + EPSBN);
  scsh[j] = sc;
  scsh[HID + j] = beta[j] - mu * sc;
}

// ---------------------------------------------------------------------------
// pool: per-graph mean of h2 (batch sorted -> register accumulate, flush on
// boundary)
// ---------------------------------------------------------------------------
#define POOL_WAVES 2048
__global__ __launch_bounds__(256) void pool_kernel(
    const float* __restrict__ h2, const int* __restrict__ batch,
    float* __restrict__ poolacc, float* __restrict__ poolcnt) {
  int wave = (blockIdx.x * blockDim.x + threadIdx.x) >> 6;
  int j = threadIdx.x & 63;
  const int chunk = (N_NODES + POOL_WAVES - 1) / POOL_WAVES;
  int n0 = wave * chunk;
  int n1 = n0 + chunk;
  n1 = n1 < N_NODES ? n1 : N_NODES;
  if (n0 >= n1) return;
  bool docnt = (j == 0);

  int curb = -1;
  float accv = 0.f, cntv = 0.f;
  for (int n = n0; n < n1; ++n) {
    float val = h2[(size_t)n * HID + j];
    int b = batch[n];
    if (b != curb) {
      if (curb >= 0) {
        unsafeAtomicAdd(&poolacc[curb * HID + j], accv);
        if (docnt) unsafeAtomicAdd(&poolcnt[curb], cntv);
      }
      curb = b;
      accv = 0.f;
      cntv = 0.f;
    }
    accv += val;
    cntv += 1.f;
  }
  if (curb >= 0) {
    unsafeAtomicAdd(&poolacc[curb * HID + j], accv);
    if (docnt) unsafeAtomicAdd(&poolcnt[curb], cntv);
  }
}

// ---------------------------------------------------------------------------
__global__ void final_kernel(const float* __restrict__ poolacc,
                             const float* __restrict__ poolcnt,
                             float* __restrict__ out) {
  int t = blockIdx.x * blockDim.x + threadIdx.x;
  if (t >= NGRAPH * HID) return;
  int b = t >> 6;
  float c = poolcnt[b];
  c = c > 1.f ? c : 1.f;
  out[t] = poolacc[t] / c;
}

// ---------------------------------------------------------------------------
extern "C" void kernel_launch(void* const* d_in, const int* in_sizes, int n_in,
                              void* d_out, int out_size, void* d_ws,
                              size_t ws_size, hipStream_t stream) {
  const float* x      = (const float*)d_in[0];
  const int*   ei     = (const int*)d_in[1];
  const int*   batch  = (const int*)d_in[2];
  const float* W1l    = (const float*)d_in[3];
  const float* b1     = (const float*)d_in[4];
  const float* W1r    = (const float*)d_in[5];
  const float* gamma1 = (const float*)d_in[6];
  const float* beta1  = (const float*)d_in[7];
  const float* W2l    = (const float*)d_in[8];
  const float* b2     = (const float*)d_in[9];
  const float* W2r    = (const float*)d_in[10];

  const int* src = ei;            // edge_index[0]
  const int* dst = ei + E_EDGES;  // edge_index[1]

  float* ws = (float*)d_ws;
  size_t off = 0;
  float* A  = ws + off; off += (size_t)N_NODES * HID;  // y1 -> z1
  float* Bb = ws + off; off += (size_t)N_NODES * HID;  // y2 -> z2
  float* Cc = ws + off; off += (size_t)N_NODES * HID;  // h_raw / h2
  // zero-region start
  int* bktcnt   = (int*)(ws + off); off += NBKT;
  float* stats  = ws + off; off += 2 * HID;
  float* poolacc= ws + off; off += NGRAPH * HID;
  float* poolcnt= ws + off; off += NGRAPH;
  size_t zero_elems = NBKT + 2 * HID + NGRAPH * HID + NGRAPH;
  // zero-region end
  float* scsh   = ws + off; off += 2 * HID;
  int* deg      = (int*)(ws + off); off += N_NODES;
  int* rowptr   = (int*)(ws + off); off += N_NODES + 1;
  int* bsum     = (int*)(ws + off); off += 128;
  int* csr      = (int*)(ws + off); off += E_EDGES;
  unsigned* bktbuf = (unsigned*)(ws + off); off += (size_t)NBKT * BKT_CAP;

  hipMemsetAsync(bktcnt, 0, zero_elems * sizeof(float), stream);

  // ---- CSR build ----
  bscatter_kernel<<<(E_EDGES + 255) / 256, 256, 0, stream>>>(src, dst, bktcnt,
                                                             bktbuf);
  bhist_kernel<<<NBKT, 256, 0, stream>>>(bktcnt, bktbuf, deg);
  scanA_kernel<<<NSCAN_BLKS, SCAN_BLK, 0, stream>>>(deg, rowptr + 1, bsum);
  scanB_kernel<<<1, 128, 0, stream>>>(bsum);
  scanC_kernel<<<(N_NODES + 255) / 256, 256, 0, stream>>>(rowptr, bsum);
  emit_kernel<<<NBKT, 256, 0, stream>>>(bktcnt, bktbuf, rowptr, csr);

  // ---- layer 1 ----
  mm1_kernel<<<(N_NODES + 63) / 64, 256, 0, stream>>>(x, W1l, W1r, A, Bb);
  gather_kernel<true><<<2048, 256, 0, stream>>>(A, csr, rowptr, Bb, b1, Cc,
                                                stats);
  bnstats_kernel<<<1, 64, 0, stream>>>(stats, gamma1, beta1, scsh);

  // ---- layer 2 ----
  mm2_kernel<<<(N_NODES + 63) / 64, 256, 0, stream>>>(Cc, scsh, W2l, W2r, A,
                                                      Bb);
  gather_kernel<false><<<2048, 256, 0, stream>>>(A, csr, rowptr, Bb, b2, Cc,
                                                 nullptr);
  pool_kernel<<<(POOL_WAVES * 64 + 255) / 256, 256, 0, stream>>>(
      Cc, batch, poolacc, poolcnt);
  final_kernel<<<2, 256, 0, stream>>>(poolacc, poolcnt, (float*)d_out);
}

// Round 5
// 380.601 us; speedup vs baseline: 2.9057x; 1.5391x over previous
//
#include <hip/hip_runtime.h>

#define N_NODES 100000
#define E_EDGES 1600000
#define DIM 128
#define HID 64
#define NGRAPH 8
#define EPSBN 1e-5f

// ---- radix partition by dst ----
#define GSHIFT 10
#define GNODES (1 << GSHIFT)                              // 1024 nodes/group
#define NGROUP ((N_NODES + GNODES - 1) >> GSHIFT)         // 98 groups
#define GCAP 20480      // mean 16327, sigma ~127 -> 32-sigma margin
#define CHUNK 2048      // edges per partition block
#define PBLK 256
#define EPT (CHUNK / PBLK)                                // 8 edges/thread
#define NCHUNK ((E_EDGES + CHUNK - 1) / CHUNK)            // 782

// ---------------------------------------------------------------------------
// partition: LDS-staged multi-split of edges into 98 dst-groups.
// Per chunk: LDS hist -> LDS scan -> reserve global space (98 atomics) ->
// LDS reorder -> near-coalesced writeout (runs of ~21 edges per group).
// token = (dst & 1023) << 17 | src   (src < 2^17)
// ---------------------------------------------------------------------------
__global__ __launch_bounds__(PBLK) void partition_kernel(
    const int* __restrict__ src, const int* __restrict__ dst,
    int* __restrict__ gcnt, unsigned* __restrict__ part) {
  __shared__ int hist[128];
  __shared__ int sc[128];
  __shared__ int scanoff[128];
  __shared__ int gbase[128];
  __shared__ unsigned buf[CHUNK];
  __shared__ unsigned char gid[CHUNK];

  int c = blockIdx.x;
  if (c >= NCHUNK) return;
  int e0 = c * CHUNK;
  int m = E_EDGES - e0;
  m = m < CHUNK ? m : CHUNK;
  int t = threadIdx.x;

  if (t < 128) hist[t] = 0;
  __syncthreads();

  int myg[EPT];
  unsigned mytok[EPT];
  int myrank[EPT];
  #pragma unroll
  for (int q = 0; q < EPT; ++q) {
    int i = t + q * PBLK;  // coalesced
    if (i < m) {
      int d = dst[e0 + i];
      int s = src[e0 + i];
      int g = d >> GSHIFT;
      myg[q] = g;
      mytok[q] = ((unsigned)(d & (GNODES - 1)) << 17) | (unsigned)s;
      myrank[q] = atomicAdd(&hist[g], 1);
    } else {
      myg[q] = -1;
    }
  }
  __syncthreads();

  // reserve global space per group; copy hist for scan
  if (t < 128) {
    sc[t] = hist[t];
    if (t < NGROUP && hist[t] > 0) gbase[t] = atomicAdd(&gcnt[t], hist[t]);
  }
  __syncthreads();
  // inclusive Hillis-Steele scan over sc[128]
  for (int off = 1; off < 128; off <<= 1) {
    int add = (t < 128 && t >= off) ? sc[t - off] : 0;
    __syncthreads();
    if (t < 128) sc[t] += add;
    __syncthreads();
  }
  if (t < 128) scanoff[t] = sc[t] - hist[t];  // exclusive
  __syncthreads();

  // LDS reorder
  #pragma unroll
  for (int q = 0; q < EPT; ++q) {
    if (myg[q] >= 0) {
      int pos = scanoff[myg[q]] + myrank[q];
      buf[pos] = mytok[q];
      gid[pos] = (unsigned char)myg[q];
    }
  }
  __syncthreads();

  // writeout: consecutive i within a group run -> consecutive global addrs
  for (int i = t; i < m; i += PBLK) {
    int g = gid[i];
    int addr = gbase[g] + (i - scanoff[g]);
    if (addr < GCAP) part[(size_t)g * GCAP + addr] = buf[i];
  }
}

// ---------------------------------------------------------------------------
// groupcsr: one 1024-thread block per group. LDS hist of 1024 nodes ->
// in-LDS scan -> coalesced rowptr write -> scatter csr via LDS cursors
// into the group's contiguous csr window (L2-resident).
// ---------------------------------------------------------------------------
__global__ __launch_bounds__(1024) void groupcsr_kernel(
    const int* __restrict__ gcnt, const unsigned* __restrict__ part,
    int* __restrict__ rowptr, int* __restrict__ csr) {
  __shared__ int hist[GNODES];
  __shared__ int excl[GNODES];
  __shared__ int sc2[128];
  int g = blockIdx.x;
  int t = threadIdx.x;

  // group bases: scan of group sizes (redundant per block, cheap)
  if (t < 128) sc2[t] = (t < NGROUP) ? min(gcnt[t], GCAP) : 0;
  __syncthreads();
  for (int off = 1; off < 128; off <<= 1) {
    int add = (t < 128 && t >= off) ? sc2[t - off] : 0;
    __syncthreads();
    if (t < 128) sc2[t] += add;
    __syncthreads();
  }
  int gbase = (g > 0) ? sc2[g - 1] : 0;

  hist[t] = 0;
  __syncthreads();

  int cnt = min(gcnt[g], GCAP);
  const unsigned* ga = part + (size_t)g * GCAP;
  for (int i = t; i < cnt; i += 1024) atomicAdd(&hist[ga[i] >> 17], 1);
  __syncthreads();

  // inclusive scan over hist[1024], in place
  int orig = hist[t];
  for (int off = 1; off < GNODES; off <<= 1) {
    int add = (t >= off) ? hist[t - off] : 0;
    __syncthreads();
    hist[t] += add;
    __syncthreads();
  }
  excl[t] = hist[t] - orig;
  __syncthreads();

  // rowptr (coalesced); n == N_NODES case handled naturally (trailing hists 0)
  int n = (g << GSHIFT) + t;
  if (n <= N_NODES) rowptr[n] = gbase + excl[t];
  if (g == 0 && t == 0) rowptr[0] = 0;
  __syncthreads();

  // scatter into group's csr window using excl as cursors
  for (int i = t; i < cnt; i += 1024) {
    unsigned p = ga[i];
    int dloc = (int)(p >> 17);
    int pos = gbase + atomicAdd(&excl[dloc], 1);
    csr[pos] = (int)(p & 0x1FFFFu);
  }
}

// ---------------------------------------------------------------------------
// mm1: y1 = x@W1l, y2 = x@W1r.  Block = 64 rows x 4 waves; wave w owns cols
// [w*16, w*16+16) of BOTH outputs (wave-uniform c0 -> scalarized W loads).
// ---------------------------------------------------------------------------
__global__ __launch_bounds__(256) void mm1_kernel(
    const float* __restrict__ x, const float* __restrict__ W1l,
    const float* __restrict__ W1r, float* __restrict__ y1,
    float* __restrict__ y2) {
  int lane = threadIdx.x & 63;
  int c0 = __builtin_amdgcn_readfirstlane((int)(threadIdx.x >> 6) << 4);
  int n = blockIdx.x * 64 + lane;
  if (n >= N_NODES) return;
  const float* xr = x + (size_t)n * DIM;

  float a1[16], a2[16];
  #pragma unroll
  for (int j = 0; j < 16; ++j) { a1[j] = 0.f; a2[j] = 0.f; }

  for (int k = 0; k < DIM; k += 4) {
    float4 xv = *reinterpret_cast<const float4*>(xr + k);
    float xs[4] = {xv.x, xv.y, xv.z, xv.w};
    #pragma unroll
    for (int kk = 0; kk < 4; ++kk) {
      const float* w1 = W1l + (size_t)(k + kk) * HID + c0;  // uniform addr
      const float* w2 = W1r + (size_t)(k + kk) * HID + c0;  // uniform addr
      float xk = xs[kk];
      #pragma unroll
      for (int j = 0; j < 16; ++j) {
        a1[j] = fmaf(xk, w1[j], a1[j]);
        a2[j] = fmaf(xk, w2[j], a2[j]);
      }
    }
  }
  float* o1 = y1 + (size_t)n * HID + c0;
  float* o2 = y2 + (size_t)n * HID + c0;
  #pragma unroll
  for (int q = 0; q < 4; ++q) {
    *reinterpret_cast<float4*>(o1 + 4 * q) =
        make_float4(a1[4*q], a1[4*q+1], a1[4*q+2], a1[4*q+3]);
    *reinterpret_cast<float4*>(o2 + 4 * q) =
        make_float4(a2[4*q], a2[4*q+1], a2[4*q+2], a2[4*q+3]);
  }
}

// ---------------------------------------------------------------------------
// mm2: h = relu(hraw*scale+shift); z1=h@W2l, z2=h@W2r. Same wave split.
// ---------------------------------------------------------------------------
__global__ __launch_bounds__(256) void mm2_kernel(
    const float* __restrict__ C, const float* __restrict__ scsh,
    const float* __restrict__ W2l, const float* __restrict__ W2r,
    float* __restrict__ z1, float* __restrict__ z2) {
  int lane = threadIdx.x & 63;
  int c0 = __builtin_amdgcn_readfirstlane((int)(threadIdx.x >> 6) << 4);
  int n = blockIdx.x * 64 + lane;
  if (n >= N_NODES) return;
  const float* hr = C + (size_t)n * HID;

  float a1[16], a2[16];
  #pragma unroll
  for (int j = 0; j < 16; ++j) { a1[j] = 0.f; a2[j] = 0.f; }

  for (int k = 0; k < HID; k += 4) {
    float4 hv = *reinterpret_cast<const float4*>(hr + k);
    float hs[4] = {hv.x, hv.y, hv.z, hv.w};
    #pragma unroll
    for (int kk = 0; kk < 4; ++kk) {
      float hk = fmaf(hs[kk], scsh[k + kk], scsh[HID + k + kk]);
      hk = hk > 0.f ? hk : 0.f;
      const float* w1 = W2l + (size_t)(k + kk) * HID + c0;  // uniform addr
      const float* w2 = W2r + (size_t)(k + kk) * HID + c0;  // uniform addr
      #pragma unroll
      for (int j = 0; j < 16; ++j) {
        a1[j] = fmaf(hk, w1[j], a1[j]);
        a2[j] = fmaf(hk, w2[j], a2[j]);
      }
    }
  }
  float* o1 = z1 + (size_t)n * HID + c0;
  float* o2 = z2 + (size_t)n * HID + c0;
  #pragma unroll
  for (int q = 0; q < 4; ++q) {
    *reinterpret_cast<float4*>(o1 + 4 * q) =
        make_float4(a1[4*q], a1[4*q+1], a1[4*q+2], a1[4*q+3]);
    *reinterpret_cast<float4*>(o2 + 4 * q) =
        make_float4(a2[4*q], a2[4*q+1], a2[4*q+2], a2[4*q+3]);
  }
}

// ---------------------------------------------------------------------------
// gather: one wave per node (grid-stride); out = mean(y[src]) + bias + other.
// STATS: per-column sum/sumsq in registers, flushed once per block.
// ---------------------------------------------------------------------------
template <bool STATS>
__global__ __launch_bounds__(256) void gather_kernel(
    const float* __restrict__ y, const int* __restrict__ csr,
    const int* __restrict__ rowptr, const float* __restrict__ other,
    const float* __restrict__ bias, float* __restrict__ outC,
    float* __restrict__ stats) {
  int lane = threadIdx.x & 63;
  int wid = (blockIdx.x * blockDim.x + threadIdx.x) >> 6;
  int nw = (gridDim.x * blockDim.x) >> 6;
  float bj = bias[lane];
  float lsum = 0.f, lsq = 0.f;

  for (int n = wid; n < N_NODES; n += nw) {
    int start = rowptr[n];
    int end = rowptr[n + 1];
    float acc = 0.f;
    for (int bse = start; bse < end; bse += 64) {
      int e = bse + lane;
      int s = (e < end) ? csr[e] : 0;
      int m = end - bse;
      m = m < 64 ? m : 64;
      float a0 = 0.f, a1 = 0.f, a2 = 0.f, a3 = 0.f;
      int i = 0;
      for (; i + 4 <= m; i += 4) {
        int s0 = __shfl(s, i);
        int s1 = __shfl(s, i + 1);
        int s2 = __shfl(s, i + 2);
        int s3 = __shfl(s, i + 3);
        a0 += y[(size_t)s0 * HID + lane];
        a1 += y[(size_t)s1 * HID + lane];
        a2 += y[(size_t)s2 * HID + lane];
        a3 += y[(size_t)s3 * HID + lane];
      }
      for (; i < m; ++i) a0 += y[(size_t)__shfl(s, i) * HID + lane];
      acc += (a0 + a1) + (a2 + a3);
    }
    int deg = end - start;
    float inv = 1.f / (float)(deg > 1 ? deg : 1);
    float val = acc * inv + bj + other[(size_t)n * HID + lane];
    outC[(size_t)n * HID + lane] = val;
    if (STATS) {
      lsum += val;
      lsq = fmaf(val, val, lsq);
    }
  }

  if (STATS) {
    __shared__ float ss[HID];
    __shared__ float sq[HID];
    int t = threadIdx.x;
    if (t < HID) { ss[t] = 0.f; sq[t] = 0.f; }
    __syncthreads();
    atomicAdd(&ss[lane], lsum);
    atomicAdd(&sq[lane], lsq);
    __syncthreads();
    if (t < HID) {
      unsafeAtomicAdd(&stats[t], ss[t]);
      unsafeAtomicAdd(&stats[HID + t], sq[t]);
    }
  }
}

// ---------------------------------------------------------------------------
__global__ void bnstats_kernel(const float* __restrict__ stats,
                               const float* __restrict__ gamma,
                               const float* __restrict__ beta,
                               float* __restrict__ scsh) {
  int j = threadIdx.x;  // 64 threads
  float inv_n = 1.0f / (float)N_NODES;
  float mu = stats[j] * inv_n;
  float var = stats[HID + j] * inv_n - mu * mu;
  float sc = gamma[j] * rsqrtf(var + EPSBN);
  scsh[j] = sc;
  scsh[HID + j] = beta[j] - mu * sc;
}

// ---------------------------------------------------------------------------
// pool: per-graph mean of h2 (batch sorted -> register accumulate)
// ---------------------------------------------------------------------------
#define POOL_WAVES 2048
__global__ __launch_bounds__(256) void pool_kernel(
    const float* __restrict__ h2, const int* __restrict__ batch,
    float* __restrict__ poolacc, float* __restrict__ poolcnt) {
  int wave = (blockIdx.x * blockDim.x + threadIdx.x) >> 6;
  int j = threadIdx.x & 63;
  const int chunk = (N_NODES + POOL_WAVES - 1) / POOL_WAVES;
  int n0 = wave * chunk;
  int n1 = n0 + chunk;
  n1 = n1 < N_NODES ? n1 : N_NODES;
  if (n0 >= n1) return;
  bool docnt = (j == 0);

  int curb = -1;
  float accv = 0.f, cntv = 0.f;
  for (int n = n0; n < n1; ++n) {
    float val = h2[(size_t)n * HID + j];
    int b = batch[n];
    if (b != curb) {
      if (curb >= 0) {
        unsafeAtomicAdd(&poolacc[curb * HID + j], accv);
        if (docnt) unsafeAtomicAdd(&poolcnt[curb], cntv);
      }
      curb = b;
      accv = 0.f;
      cntv = 0.f;
    }
    accv += val;
    cntv += 1.f;
  }
  if (curb >= 0) {
    unsafeAtomicAdd(&poolacc[curb * HID + j], accv);
    if (docnt) unsafeAtomicAdd(&poolcnt[curb], cntv);
  }
}

// ---------------------------------------------------------------------------
__global__ void final_kernel(const float* __restrict__ poolacc,
                             const float* __restrict__ poolcnt,
                             float* __restrict__ out) {
  int t = blockIdx.x * blockDim.x + threadIdx.x;
  if (t >= NGRAPH * HID) return;
  int b = t >> 6;
  float c = poolcnt[b];
  c = c > 1.f ? c : 1.f;
  out[t] = poolacc[t] / c;
}

// ---------------------------------------------------------------------------
extern "C" void kernel_launch(void* const* d_in, const int* in_sizes, int n_in,
                              void* d_out, int out_size, void* d_ws,
                              size_t ws_size, hipStream_t stream) {
  const float* x      = (const float*)d_in[0];
  const int*   ei     = (const int*)d_in[1];
  const int*   batch  = (const int*)d_in[2];
  const float* W1l    = (const float*)d_in[3];
  const float* b1     = (const float*)d_in[4];
  const float* W1r    = (const float*)d_in[5];
  const float* gamma1 = (const float*)d_in[6];
  const float* beta1  = (const float*)d_in[7];
  const float* W2l    = (const float*)d_in[8];
  const float* b2     = (const float*)d_in[9];
  const float* W2r    = (const float*)d_in[10];

  const int* src = ei;            // edge_index[0]
  const int* dst = ei + E_EDGES;  // edge_index[1]

  float* ws = (float*)d_ws;
  size_t off = 0;
  float* A  = ws + off; off += (size_t)N_NODES * HID;  // y1 -> z1
  float* Bb = ws + off; off += (size_t)N_NODES * HID;  // y2 -> z2
  float* Cc = ws + off; off += (size_t)N_NODES * HID;  // h_raw / h2
  // zero-region start
  int* gcnt     = (int*)(ws + off); off += NGROUP;
  float* stats  = ws + off; off += 2 * HID;
  float* poolacc= ws + off; off += NGRAPH * HID;
  float* poolcnt= ws + off; off += NGRAPH;
  size_t zero_elems = NGROUP + 2 * HID + NGRAPH * HID + NGRAPH;
  // zero-region end
  float* scsh   = ws + off; off += 2 * HID;
  int* rowptr   = (int*)(ws + off); off += N_NODES + 1;
  int* csr      = (int*)(ws + off); off += E_EDGES;
  unsigned* part = (unsigned*)(ws + off); off += (size_t)NGROUP * GCAP;

  hipMemsetAsync(gcnt, 0, zero_elems * sizeof(float), stream);

  // ---- CSR build: 2-pass radix partition ----
  partition_kernel<<<NCHUNK, PBLK, 0, stream>>>(src, dst, gcnt, part);
  groupcsr_kernel<<<NGROUP, 1024, 0, stream>>>(gcnt, part, rowptr, csr);

  // ---- layer 1 ----
  mm1_kernel<<<(N_NODES + 63) / 64, 256, 0, stream>>>(x, W1l, W1r, A, Bb);
  gather_kernel<true><<<2048, 256, 0, stream>>>(A, csr, rowptr, Bb, b1, Cc,
                                                stats);
  bnstats_kernel<<<1, 64, 0, stream>>>(stats, gamma1, beta1, scsh);

  // ---- layer 2 ----
  mm2_kernel<<<(N_NODES + 63) / 64, 256, 0, stream>>>(Cc, scsh, W2l, W2r, A,
                                                      Bb);
  gather_kernel<false><<<2048, 256, 0, stream>>>(A, csr, rowptr, Bb, b2, Cc,
                                                 nullptr);
  pool_kernel<<<(POOL_WAVES * 64 + 255) / 256, 256, 0, stream>>>(
      Cc, batch, poolacc, poolcnt);
  final_kernel<<<2, 256, 0, stream>>>(poolacc, poolcnt, (float*)d_out);
}